// Round 11
// baseline (336.094 us; speedup 1.0000x reference)
//
#include <hip/hip_runtime.h>
#include <hip/hip_bf16.h>

typedef __attribute__((ext_vector_type(8))) short short8;
typedef __attribute__((ext_vector_type(8))) unsigned short ushort8;
typedef __attribute__((ext_vector_type(4))) float f32x4;
typedef unsigned short ushort;

#define K_DIM 4096
#define N_DIM 4096
#define BK 32
#define NT (K_DIM / BK)   // 128 K-tiles

// ---------- numerics helpers (exactly mirror the reference) ----------

__device__ __forceinline__ float e4m3_rne(float v) {
    if (v >= 0.015625f) {
        unsigned u = __float_as_uint(v);
        unsigned lsb = (u >> 20) & 1u;
        u = (u + 0x7FFFFu + lsb) & 0xFFF00000u;
        return __uint_as_float(u);
    }
    return rintf(v * 512.0f) * 0.001953125f;
}

__device__ __forceinline__ float e2m1_level(float m) {
    float lv = 0.0f;
    lv = (m > 0.25f) ? 0.5f : lv;
    lv = (m > 0.75f) ? 1.0f : lv;
    lv = (m > 1.25f) ? 1.5f : lv;
    lv = (m > 1.75f) ? 2.0f : lv;
    lv = (m > 2.5f)  ? 3.0f : lv;
    lv = (m > 3.5f)  ? 4.0f : lv;
    lv = (m > 5.0f)  ? 6.0f : lv;
    return lv;
}

__device__ __forceinline__ ushort f32_to_bf16_bits(float f) {
    unsigned u = __float_as_uint(f);
    return (ushort)((u + 0x7FFFu + ((u >> 16) & 1u)) >> 16);
}

// ---------- small kernels ----------

__global__ void wamax_kernel(const float* __restrict__ w, unsigned* amax_bits, int n4) {
    float m = 0.f;
    const f32x4* w4 = (const f32x4*)w;
    for (int i = blockIdx.x * blockDim.x + threadIdx.x; i < n4; i += gridDim.x * blockDim.x) {
        f32x4 v = w4[i];
        m = fmaxf(m, fmaxf(fmaxf(fabsf(v.x), fabsf(v.y)), fmaxf(fabsf(v.z), fabsf(v.w))));
    }
#pragma unroll
    for (int off = 32; off >= 1; off >>= 1)
        m = fmaxf(m, __shfl_down(m, off));
    __shared__ float red[4];
    const int lane = threadIdx.x & 63, wv = threadIdx.x >> 6;
    if (lane == 0) red[wv] = m;
    __syncthreads();
    if (threadIdx.x == 0) {
        m = fmaxf(fmaxf(red[0], red[1]), fmaxf(red[2], red[3]));
        atomicMax(amax_bits, __float_as_uint(m));
    }
}

__global__ void quant16_kernel(const float* __restrict__ src,
                               const float* __restrict__ s2_ptr,
                               const unsigned* __restrict__ amax_bits,
                               ushort* __restrict__ dst, int nblk) {
    int t = blockIdx.x * blockDim.x + threadIdx.x;
    if (t >= nblk) return;
    float s2;
    if (s2_ptr) s2 = *s2_ptr;
    else        s2 = 2688.0f / __uint_as_float(*amax_bits);

    const f32x4* s = (const f32x4*)src + (size_t)t * 4;
    float vals[16];
    f32x4 v0 = s[0], v1 = s[1], v2 = s[2], v3 = s[3];
#pragma unroll
    for (int i = 0; i < 4; ++i) {
        vals[i] = v0[i]; vals[4 + i] = v1[i]; vals[8 + i] = v2[i]; vals[12 + i] = v3[i];
    }
    float amax = 0.f;
#pragma unroll
    for (int i = 0; i < 16; ++i) amax = fmaxf(amax, fabsf(vals[i]));

    float sf = e4m3_rne(fminf(amax * s2 / 6.0f, 448.0f));
    float scale = sf / s2;

    ushort8 o0, o1;
    if (scale > 0.f) {
#pragma unroll
        for (int i = 0; i < 16; ++i) {
            float r = vals[i] / scale;
            float m = fminf(fabsf(r), 6.0f);
            float q = copysignf(e2m1_level(m), r);
            ushort b = f32_to_bf16_bits(q * scale);
            if (i < 8) o0[i] = b; else o1[i - 8] = b;
        }
    } else {
#pragma unroll
        for (int i = 0; i < 8; ++i) { o0[i] = 0; o1[i] = 0; }
    }
    ushort8* d8 = (ushort8*)(dst + (size_t)t * 16);
    d8[0] = o0;
    d8[1] = o1;
}

// ---------- GEMM: C[M,N] = A[M,K]*B[N,K]^T + bias ----------
// 128x256 tile, BK=32, 8 waves (2Mx4N), wave output 64x64 (acc=64 VGPR),
// ring-3 LDS (3 x 24 KB = 72 KB) -> TWO blocks resident per CU
// (__launch_bounds__(512,4)): when one block bursts its LDS reads at the
// barrier, the co-resident block's MFMA fills the matrix pipe (m114 overlap
// — the mechanism R8/R10's single-block 54% plateau was missing).
// Counted vmcnt(3) per tile (stage t+2 during t; ring-3 never drains);
// counted lgkmcnt(3/2/1/0) before each 4-MFMA column cluster.

__device__ __forceinline__ void gload16(const ushort* g, ushort* l) {
    __builtin_amdgcn_global_load_lds(
        (const __attribute__((address_space(1))) void*)g,
        (__attribute__((address_space(3))) void*)l, 16, 0, 0);
}

#define VM3 asm volatile("s_waitcnt vmcnt(3)" ::: "memory")
#define VM0 asm volatile("s_waitcnt vmcnt(0)" ::: "memory")
#define LGW(N) do { asm volatile("s_waitcnt lgkmcnt(" #N ")" ::: "memory"); \
                    __builtin_amdgcn_sched_barrier(0); } while (0)
#define BAR asm volatile("s_barrier" ::: "memory")

// buffer size in ushorts: A[128][32] + B[256][32]
#define BUFSZ 12288
#define BOFF_B 4096

__global__ __launch_bounds__(512, 4) void gemm8(
    const ushort* __restrict__ Aq, const ushort* __restrict__ Bq,
    const float* __restrict__ bias, float* __restrict__ C) {
    __shared__ ushort lds[3 * BUFSZ];   // 72 KB

    const int tid  = threadIdx.x;
    const int lane = tid & 63;
    const int wave = tid >> 6;
    const int wr = wave >> 2;    // 0..1  (64-row half of the 128-row A tile)
    const int wc = wave & 3;     // 0..3  (64-col group of the 256-col B tile)

    // supertile swizzle: 256 consecutive ranks = 16(by) x 16(bx) region
    // (A 16x128 rows = 16 MB + B full 4096 cols = 32 MB -> 48 MB, fits L3)
    const int swz = blockIdx.x;
    const int grp = swz >> 8, lcl = swz & 255;
    const int by = grp * 16 + (lcl & 15);   // 0..63
    const int bx = lcl >> 4;                // 0..15
    const int bm = by * 128, bn = bx * 256;

    // ---- staging: LDS linear in tid order; global source pre-swizzled ----
    // slot p of row r holds k-group cg = (p - (r>>1)) & 3   (R5, 0 conflicts)
    const int r0  = tid >> 2;                       // 0..127
    const int cg0 = ((tid & 3) - ((r0 >> 1) & 3)) & 3;
    const ushort* sA0 = Aq + (size_t)(bm + r0) * K_DIM + cg0 * 8;
    const ushort* sB0 = Bq + (size_t)(bn + r0) * K_DIM + cg0 * 8;
    ushort* dA0 = &lds[tid * 8];                 // A region base (+buf offset)
    ushort* dB0 = &lds[BOFF_B + tid * 8];        // B rows 0-127; rows 128+ at +4096

    // ---- fragment read offsets (swizzled): p = (kgrp + (row>>1)) & 3 ----
    const int pr   = ((lane >> 4) + ((lane & 15) >> 1)) & 3;
    const int idxA = (wr * 64 + (lane & 15)) * 32 + pr * 8;
    const int idxB = BOFF_B + (wc * 64 + (lane & 15)) * 32 + pr * 8;

    f32x4 acc[4][4];
#pragma unroll
    for (int m = 0; m < 4; ++m)
#pragma unroll
        for (int n = 0; n < 4; ++n) acc[m][n] = (f32x4)(0.f);

    short8 af[4], bfr[4];

// stage tile t into buffer bb (compile-time): A 1 gload, B 2 gloads
#define STAGE(t, bb) {                                                        \
        const size_t ko = (size_t)(t) * BK;                                   \
        gload16(sA0 + ko, dA0 + (bb));                                        \
        gload16(sB0 + ko, dB0 + (bb));                                        \
        gload16(sB0 + (size_t)128 * K_DIM + ko, dB0 + (bb) + 4096); }

// tile body: buffer bb (compile-time), optional staging of t+2 into bs
#define TILE(bb, STAGE_STMT, VMW)                                             \
    {                                                                         \
        VMW; BAR;                                                             \
        _Pragma("unroll") for (int m = 0; m < 4; ++m)                         \
            af[m] = *(const short8*)&lds[(bb) + idxA + m * 512];              \
        _Pragma("unroll") for (int n = 0; n < 4; ++n)                         \
            bfr[n] = *(const short8*)&lds[(bb) + idxB + n * 512];             \
        STAGE_STMT;                                                           \
        LGW(3);                                                               \
        __builtin_amdgcn_s_setprio(1);                                        \
        _Pragma("unroll") for (int m = 0; m < 4; ++m)                         \
            acc[m][0] = __builtin_amdgcn_mfma_f32_16x16x32_bf16(af[m], bfr[0], acc[m][0], 0, 0, 0); \
        __builtin_amdgcn_s_setprio(0);                                        \
        LGW(2);                                                               \
        __builtin_amdgcn_s_setprio(1);                                        \
        _Pragma("unroll") for (int m = 0; m < 4; ++m)                         \
            acc[m][1] = __builtin_amdgcn_mfma_f32_16x16x32_bf16(af[m], bfr[1], acc[m][1], 0, 0, 0); \
        __builtin_amdgcn_s_setprio(0);                                        \
        LGW(1);                                                               \
        __builtin_amdgcn_s_setprio(1);                                        \
        _Pragma("unroll") for (int m = 0; m < 4; ++m)                         \
            acc[m][2] = __builtin_amdgcn_mfma_f32_16x16x32_bf16(af[m], bfr[2], acc[m][2], 0, 0, 0); \
        __builtin_amdgcn_s_setprio(0);                                        \
        LGW(0);                                                               \
        __builtin_amdgcn_s_setprio(1);                                        \
        _Pragma("unroll") for (int m = 0; m < 4; ++m)                         \
            acc[m][3] = __builtin_amdgcn_mfma_f32_16x16x32_bf16(af[m], bfr[3], acc[m][3], 0, 0, 0); \
        __builtin_amdgcn_s_setprio(0);                                        \
    }

#define NOPS ((void)0)

    // prologue: stage tiles 0,1 (6 loads)
    STAGE(0, 0); STAGE(1, BUFSZ);

    // main loop: t = 0..125 (126 = 3*42), buffers 0/1/2 compile-time.
    // tile t stages t+2 into buf (t+2)%3; vmcnt(3) waits buf(t)'s 3 loads
    // (oldest) while buf(t+1)'s 3 stay in flight.
#pragma unroll 1
    for (int u = 0; u < (NT - 2) / 3; ++u) {
        const int t0 = u * 3;
        TILE(0,         STAGE(t0 + 2, 2 * BUFSZ), VM3);
        TILE(BUFSZ,     STAGE(t0 + 3, 0),         VM3);
        TILE(2 * BUFSZ, STAGE(t0 + 4, BUFSZ),     VM3);
    }
    // t = 126 (buf 0): no staging; t = 127 (buf 1): full drain
    TILE(0,     NOPS, VM3);
    TILE(BUFSZ, NOPS, VM0);

    // ---- epilogue: C/D layout col=lane&15, row=(lane>>4)*4+reg ----
    const int fq = lane >> 4, fr = lane & 15;
    const int colb = bn + wc * 64 + fr;
    float bv[4];
#pragma unroll
    for (int n = 0; n < 4; ++n) bv[n] = bias[colb + n * 16];
#pragma unroll
    for (int m = 0; m < 4; ++m)
#pragma unroll
        for (int r = 0; r < 4; ++r) {
            const int row = bm + wr * 64 + m * 16 + fq * 4 + r;
            float* Cr = C + (size_t)row * N_DIM + colb;
#pragma unroll
            for (int n = 0; n < 4; ++n) Cr[n * 16] = acc[m][n][r] + bv[n];
        }
#undef STAGE
#undef TILE
#undef NOPS
}

// ---------- launcher ----------

extern "C" void kernel_launch(void* const* d_in, const int* in_sizes, int n_in,
                              void* d_out, int out_size, void* d_ws, size_t ws_size,
                              hipStream_t stream) {
    const float* x     = (const float*)d_in[0];
    const float* w     = (const float*)d_in[1];
    const float* bias  = (const float*)d_in[2];
    const float* s_in2 = (const float*)d_in[3];
    float* out = (float*)d_out;

    const int M = in_sizes[0] / K_DIM;   // 8192

    unsigned* amax_bits = (unsigned*)d_ws;
    ushort* xq = (ushort*)((char*)d_ws + 256);
    ushort* wq = (ushort*)((char*)d_ws + 256 + (size_t)M * K_DIM * 2);

    hipMemsetAsync(amax_bits, 0, 4, stream);
    wamax_kernel<<<1024, 256, 0, stream>>>(w, amax_bits, (N_DIM * K_DIM) / 4);

    const int nblk_x = (M * K_DIM) / 16;
    quant16_kernel<<<nblk_x / 256, 256, 0, stream>>>(x, s_in2, nullptr, xq, nblk_x);
    const int nblk_w = (N_DIM * K_DIM) / 16;
    quant16_kernel<<<nblk_w / 256, 256, 0, stream>>>(w, nullptr, amax_bits, wq, nblk_w);

    const int nwg = (M / 128) * (N_DIM / 256);   // 1024
    gemm8<<<nwg, 512, 0, stream>>>(xq, wq, bias, out);
}

// Round 12
// 290.859 us; speedup vs baseline: 1.1555x; 1.1555x over previous
//
#include <hip/hip_runtime.h>
#include <hip/hip_bf16.h>

typedef __attribute__((ext_vector_type(8))) short short8;
typedef __attribute__((ext_vector_type(8))) unsigned short ushort8;
typedef __attribute__((ext_vector_type(4))) float f32x4;
typedef unsigned short ushort;

#define K_DIM 4096
#define N_DIM 4096
#define BK 32
#define NT (K_DIM / BK)   // 128 K-tiles

// ---------- numerics helpers (exactly mirror the reference) ----------

__device__ __forceinline__ float e4m3_rne(float v) {
    if (v >= 0.015625f) {
        unsigned u = __float_as_uint(v);
        unsigned lsb = (u >> 20) & 1u;
        u = (u + 0x7FFFFu + lsb) & 0xFFF00000u;
        return __uint_as_float(u);
    }
    return rintf(v * 512.0f) * 0.001953125f;
}

__device__ __forceinline__ float e2m1_level(float m) {
    float lv = 0.0f;
    lv = (m > 0.25f) ? 0.5f : lv;
    lv = (m > 0.75f) ? 1.0f : lv;
    lv = (m > 1.25f) ? 1.5f : lv;
    lv = (m > 1.75f) ? 2.0f : lv;
    lv = (m > 2.5f)  ? 3.0f : lv;
    lv = (m > 3.5f)  ? 4.0f : lv;
    lv = (m > 5.0f)  ? 6.0f : lv;
    return lv;
}

__device__ __forceinline__ ushort f32_to_bf16_bits(float f) {
    unsigned u = __float_as_uint(f);
    return (ushort)((u + 0x7FFFu + ((u >> 16) & 1u)) >> 16);
}

// ---------- small kernels ----------

__global__ void wamax_kernel(const float* __restrict__ w, unsigned* amax_bits, int n4) {
    float m = 0.f;
    const f32x4* w4 = (const f32x4*)w;
    for (int i = blockIdx.x * blockDim.x + threadIdx.x; i < n4; i += gridDim.x * blockDim.x) {
        f32x4 v = w4[i];
        m = fmaxf(m, fmaxf(fmaxf(fabsf(v.x), fabsf(v.y)), fmaxf(fabsf(v.z), fabsf(v.w))));
    }
#pragma unroll
    for (int off = 32; off >= 1; off >>= 1)
        m = fmaxf(m, __shfl_down(m, off));
    __shared__ float red[4];
    const int lane = threadIdx.x & 63, wv = threadIdx.x >> 6;
    if (lane == 0) red[wv] = m;
    __syncthreads();
    if (threadIdx.x == 0) {
        m = fmaxf(fmaxf(red[0], red[1]), fmaxf(red[2], red[3]));
        atomicMax(amax_bits, __float_as_uint(m));
    }
}

// one thread = one 16-elem block; first nx blocks quantize x, rest quantize w
__global__ void quant_both_kernel(const float* __restrict__ x,
                                  const float* __restrict__ w,
                                  const float* __restrict__ s2_ptr,
                                  const unsigned* __restrict__ amax_bits,
                                  ushort* __restrict__ xq,
                                  ushort* __restrict__ wq, int nx, int ntot) {
    int t = blockIdx.x * blockDim.x + threadIdx.x;
    if (t >= ntot) return;
    const float* src;
    ushort* dst;
    float s2;
    if (t < nx) {
        src = x; dst = xq; s2 = *s2_ptr;
    } else {
        src = w; dst = wq; t -= nx;
        s2 = 2688.0f / __uint_as_float(*amax_bits);   // (448*6)/amax
    }

    const f32x4* s = (const f32x4*)src + (size_t)t * 4;
    float vals[16];
    f32x4 v0 = s[0], v1 = s[1], v2 = s[2], v3 = s[3];
#pragma unroll
    for (int i = 0; i < 4; ++i) {
        vals[i] = v0[i]; vals[4 + i] = v1[i]; vals[8 + i] = v2[i]; vals[12 + i] = v3[i];
    }
    float amax = 0.f;
#pragma unroll
    for (int i = 0; i < 16; ++i) amax = fmaxf(amax, fabsf(vals[i]));

    float sf = e4m3_rne(fminf(amax * s2 / 6.0f, 448.0f));
    float scale = sf / s2;

    ushort8 o0, o1;
    if (scale > 0.f) {
#pragma unroll
        for (int i = 0; i < 16; ++i) {
            float r = vals[i] / scale;
            float m = fminf(fabsf(r), 6.0f);
            float q = copysignf(e2m1_level(m), r);
            ushort b = f32_to_bf16_bits(q * scale);
            if (i < 8) o0[i] = b; else o1[i - 8] = b;
        }
    } else {
#pragma unroll
        for (int i = 0; i < 8; ++i) { o0[i] = 0; o1[i] = 0; }
    }
    ushort8* d8 = (ushort8*)(dst + (size_t)t * 16);
    d8[0] = o0;
    d8[1] = o1;
}

// ---------- GEMM: C[M,N] = A[M,K]*B[N,K]^T + bias ----------
// 256x256 tile, BK=32, 8 waves (2Mx4N), 4-deep LDS ring, one VM4+BAR per
// tile (2-tile vmcnt slack), reads issued one half-tile AHEAD in program
// order. NO explicit lgkm waits / sched_barriers: ds_reads are plain C++
// loads, so the compiler emits precise counted lgkmcnt itself (m97) and is
// free to interleave MFMA with the next fragment reads (R8/R10's pins were
// the m141 anti-pattern).

__device__ __forceinline__ void gload16(const ushort* g, ushort* l) {
    __builtin_amdgcn_global_load_lds(
        (const __attribute__((address_space(1))) void*)g,
        (__attribute__((address_space(3))) void*)l, 16, 0, 0);
}

#define VM4 asm volatile("s_waitcnt vmcnt(4)" ::: "memory")
#define VM0 asm volatile("s_waitcnt vmcnt(0)" ::: "memory")
#define BAR asm volatile("s_barrier" ::: "memory")

__global__ __launch_bounds__(512, 2) void gemm8(
    const ushort* __restrict__ Aq, const ushort* __restrict__ Bq,
    const float* __restrict__ bias, float* __restrict__ C) {
    // 4 ring buffers x (A 256x32 + B 256x32) bf16 = 4 x 32 KB = 128 KB
    __shared__ ushort lds[4 * 16384];

    const int tid  = threadIdx.x;
    const int lane = tid & 63;
    const int wave = tid >> 6;
    const int wr = wave >> 2;    // 0..1  (128-row half of A)
    const int wc = wave & 3;     // 0..3  (64-col group of B)

    // supertile swizzle: 256 consecutive ranks = 16(by) x 16(bx) region (64 MB set)
    const int swz = blockIdx.x;
    const int grp = swz >> 8, lcl = swz & 255;
    const int by = grp * 16 + (lcl & 15);
    const int bx = lcl >> 4;
    const int bm = by * 256, bn = bx * 256;

    // ---- staging: LDS linear in tid order; global source pre-swizzled ----
    // slot p of row r holds k-group cg = (p - (r>>1)) & 3   (R5, 0 conflicts)
    const int r0  = tid >> 2;                       // 0..127
    const int cg0 = ((tid & 3) - ((r0 >> 1) & 3)) & 3;
    const ushort* sA0 = Aq + (size_t)(bm + r0) * K_DIM + cg0 * 8;
    const ushort* sB0 = Bq + (size_t)(bn + r0) * K_DIM + cg0 * 8;
    ushort* dA0 = &lds[wave * 512];            // + buf*16384 ; rows 128.. at +4096
    ushort* dB0 = &lds[8192 + wave * 512];

    // ---- fragment read offsets (swizzled): p = (kgrp + (row>>1)) & 3 ----
    const int pr   = ((lane >> 4) + ((lane & 15) >> 1)) & 3;
    const int idxA = (wr * 128 + (lane & 15)) * 32 + pr * 8;
    const int idxB = 8192 + (wc * 64 + (lane & 15)) * 32 + pr * 8;

    f32x4 acc[8][4];
#pragma unroll
    for (int m = 0; m < 8; ++m)
#pragma unroll
        for (int n = 0; n < 4; ++n) acc[m][n] = (f32x4)(0.f);

    short8 af[8], bfr[4];

#define SA(t) { const size_t ko = (size_t)(t) * BK; const int bb = ((t) & 3) * 16384; \
    gload16(sA0 + ko, dA0 + bb); gload16(sA0 + (size_t)128 * K_DIM + ko, dA0 + bb + 4096); }
#define SB(t) { const size_t ko = (size_t)(t) * BK; const int bb = ((t) & 3) * 16384; \
    gload16(sB0 + ko, dB0 + bb); gload16(sB0 + (size_t)128 * K_DIM + ko, dB0 + bb + 4096); }

#define READ_ALO(bb) _Pragma("unroll") for (int m = 0; m < 4; ++m) \
        af[m] = *(const short8*)&lds[(bb) + idxA + m * 512];
#define READ_AHI(bb) _Pragma("unroll") for (int m = 0; m < 4; ++m) \
        af[4 + m] = *(const short8*)&lds[(bb) + idxA + (4 + m) * 512];
#define READ_B(bb)   _Pragma("unroll") for (int n = 0; n < 4; ++n) \
        bfr[n] = *(const short8*)&lds[(bb) + idxB + n * 512];

#define MML                                                                   \
    __builtin_amdgcn_s_setprio(1);                                            \
    _Pragma("unroll") for (int m = 0; m < 4; ++m)                             \
    _Pragma("unroll") for (int n = 0; n < 4; ++n)                             \
        acc[m][n] = __builtin_amdgcn_mfma_f32_16x16x32_bf16(af[m], bfr[n], acc[m][n], 0, 0, 0); \
    __builtin_amdgcn_s_setprio(0);
#define MMH                                                                   \
    __builtin_amdgcn_s_setprio(1);                                            \
    _Pragma("unroll") for (int m = 4; m < 8; ++m)                             \
    _Pragma("unroll") for (int n = 0; n < 4; ++n)                             \
        acc[m][n] = __builtin_amdgcn_mfma_f32_16x16x32_bf16(af[m], bfr[n], acc[m][n], 0, 0, 0); \
    __builtin_amdgcn_s_setprio(0);

    // prologue: 3 tiles staged (12 loads); drain buf0+buf1; prime tile-0 low reads
    SA(0); SB(0); SA(1); SB(1); SA(2); SB(2);
    VM4; BAR;                      // buf0,buf1 landed block-wide; buf2 (4) flying
    READ_ALO(0); READ_B(0);

#pragma unroll 1
    for (int t = 0; t <= NT - 4; ++t) {
        const int bb  = (t & 3) * 16384;
        const int bb1 = ((t + 1) & 3) * 16384;
        VM4; BAR;                  // buf(t+1) published block-wide
        READ_AHI(bb);              // reads for MMH(t)
        SA(t + 3);
        MML;                       // af0-3,bfr (read at end of prev tile)
        READ_ALO(bb1);
        SB(t + 3);
        MMH;
        READ_B(bb1);
    }
    {   // t = NT-3: no staging
        const int bb  = ((NT - 3) & 3) * 16384;
        const int bb1 = ((NT - 2) & 3) * 16384;
        VM4; BAR;                  // buf(NT-2) published; buf(NT-1) (4) flying
        READ_AHI(bb);
        MML;
        READ_ALO(bb1);
        MMH;
        READ_B(bb1);
    }
    {   // t = NT-2
        const int bb  = ((NT - 2) & 3) * 16384;
        const int bb1 = ((NT - 1) & 3) * 16384;
        VM0; BAR;                  // buf(NT-1) landed block-wide
        READ_AHI(bb);
        MML;
        READ_ALO(bb1);
        MMH;
        READ_B(bb1);
    }
    {   // t = NT-1 (all staged+published)
        const int bb = ((NT - 1) & 3) * 16384;
        READ_AHI(bb);
        MML;
        MMH;
    }

    // ---- epilogue: C/D layout col=lane&15, row=(lane>>4)*4+reg ----
    const int fq = lane >> 4, fr = lane & 15;
    float bv[4];
#pragma unroll
    for (int n = 0; n < 4; ++n) bv[n] = bias[bn + wc * 64 + n * 16 + fr];
#pragma unroll
    for (int m = 0; m < 8; ++m)
#pragma unroll
        for (int r = 0; r < 4; ++r) {
            const int row = bm + wr * 128 + m * 16 + fq * 4 + r;
            float* Cr = C + (size_t)row * N_DIM + bn + wc * 64 + fr;
#pragma unroll
            for (int n = 0; n < 4; ++n) Cr[n * 16] = acc[m][n][r] + bv[n];
        }
#undef SA
#undef SB
#undef READ_ALO
#undef READ_AHI
#undef READ_B
#undef MML
#undef MMH
}

// ---------- launcher ----------

extern "C" void kernel_launch(void* const* d_in, const int* in_sizes, int n_in,
                              void* d_out, int out_size, void* d_ws, size_t ws_size,
                              hipStream_t stream) {
    const float* x     = (const float*)d_in[0];
    const float* w     = (const float*)d_in[1];
    const float* bias  = (const float*)d_in[2];
    const float* s_in2 = (const float*)d_in[3];
    float* out = (float*)d_out;

    const int M = in_sizes[0] / K_DIM;   // 8192

    unsigned* amax_bits = (unsigned*)d_ws;
    ushort* xq = (ushort*)((char*)d_ws + 256);
    ushort* wq = (ushort*)((char*)d_ws + 256 + (size_t)M * K_DIM * 2);

    hipMemsetAsync(amax_bits, 0, 4, stream);
    wamax_kernel<<<1024, 256, 0, stream>>>(w, amax_bits, (N_DIM * K_DIM) / 4);

    const int nx = (M * K_DIM) / 16;             // x blocks
    const int nw = (N_DIM * K_DIM) / 16;         // w blocks
    quant_both_kernel<<<(nx + nw) / 256, 256, 0, stream>>>(
        x, w, s_in2, amax_bits, xq, wq, nx, nx + nw);

    const int nwg = (M / 256) * (N_DIM / 256);   // 512
    gemm8<<<nwg, 512, 0, stream>>>(xq, wq, bias, out);
}